// Round 13
// baseline (513.946 us; speedup 1.0000x reference)
//
#include <hip/hip_runtime.h>

// ---------------------------------------------------------------------------
// 2-layer GCN (PyG GCNConv) N=100000, E=1600000, 128->128->64.
//
// Round 13 == round 12 kernel resubmitted (round 12 hit GPUAcquisitionTimeout;
// never ran). Permute writes ONLY srcs (norm recomputed in gathers from L2-
// resident dinv) -> half the random-scatter dirty lines; cursor initialized
// via d2d copy of off. Gathers unrolled x8. MFMA bf16 GEMMs unchanged
// (verified r11: absmax 3.9e-3).
// Dropout = jax.random.bernoulli(key(42),0.5), partitionable threefry:
// draw_i = o0^o1 of TF2x32(0,i), keep iff top bit clear.  [verified r5]
// ---------------------------------------------------------------------------

constexpr int NN    = 100000;
constexpr int NE    = 1600000;
constexpr int SCAN_CHUNK = 2048;
constexpr int NSCAN = (NN + SCAN_CHUNK - 1) / SCAN_CHUNK;  // 49

typedef __attribute__((ext_vector_type(8))) short short8v;
typedef __attribute__((ext_vector_type(4))) float f32x4;

__device__ __forceinline__ float bf2f(unsigned short u) {
  return __uint_as_float(((unsigned)u) << 16);
}
__device__ __forceinline__ unsigned short f2bf(float f) {
  unsigned x = __float_as_uint(f);
  return (unsigned short)((x + 0x7fffu + ((x >> 16) & 1u)) >> 16);
}
__device__ __forceinline__ float lo16(unsigned p) { return bf2f((unsigned short)(p & 0xffffu)); }
__device__ __forceinline__ float hi16(unsigned p) { return bf2f((unsigned short)(p >> 16)); }

__device__ __forceinline__ unsigned tf_rotl(unsigned x, int r) {
  return (x << r) | (x >> (32 - r));
}

// Threefry-2x32, 20 rounds, key (0, 42) == jax.random.key(42)
__device__ __forceinline__ void threefry2x32_0_42(unsigned in0, unsigned in1,
                                                  unsigned& o0, unsigned& o1) {
  const unsigned K0 = 0u, K1 = 42u;
  const unsigned K2 = 0x1BD11BDAu ^ K0 ^ K1;
  unsigned x0 = in0 + K0, x1 = in1 + K1;
#define TFR(r) { x0 += x1; x1 = tf_rotl(x1, r); x1 ^= x0; }
  TFR(13) TFR(15) TFR(26) TFR(6)
  x0 += K1; x1 += K2 + 1u;
  TFR(17) TFR(29) TFR(16) TFR(24)
  x0 += K2; x1 += K0 + 2u;
  TFR(13) TFR(15) TFR(26) TFR(6)
  x0 += K0; x1 += K1 + 3u;
  TFR(17) TFR(29) TFR(16) TFR(24)
  x0 += K1; x1 += K2 + 4u;
  TFR(13) TFR(15) TFR(26) TFR(6)
  x0 += K2; x1 += K0 + 5u;
#undef TFR
  o0 = x0; o1 = x1;
}

__device__ __forceinline__ bool dropout_keep(unsigned i) {
  unsigned a, b; threefry2x32_0_42(0u, i, a, b);
  return ((a ^ b) >> 31) == 0u;
}

// ---------------------------------------------------------------------------
// CSR build
// ---------------------------------------------------------------------------

__global__ __launch_bounds__(256) void hist_kernel(const int* __restrict__ dst,
                                                   int* __restrict__ cnt) {
  int e = blockIdx.x * 256 + threadIdx.x;
  if (e < NE) atomicAdd(&cnt[dst[e]], 1);
}

__global__ __launch_bounds__(256) void scan1_kernel(const int* __restrict__ cnt,
                                                    int* __restrict__ off,
                                                    int* __restrict__ blksum,
                                                    float* __restrict__ dinv) {
  __shared__ int tsum[256];
  const int base = blockIdx.x * SCAN_CHUNK + threadIdx.x * 8;
  int v[8]; int s = 0;
#pragma unroll
  for (int j = 0; j < 8; j++) {
    int idx = base + j;
    v[j] = (idx < NN) ? cnt[idx] : 0;
    s += v[j];
    if (idx < NN) dinv[idx] = rsqrtf((float)v[j] + 1.0f);  // +1 self-loop
  }
  tsum[threadIdx.x] = s;
  __syncthreads();
  for (int d = 1; d < 256; d <<= 1) {
    int t = (threadIdx.x >= d) ? tsum[threadIdx.x - d] : 0;
    __syncthreads();
    tsum[threadIdx.x] += t;
    __syncthreads();
  }
  int run = tsum[threadIdx.x] - s;  // exclusive
  if (threadIdx.x == 255) blksum[blockIdx.x] = tsum[255];
#pragma unroll
  for (int j = 0; j < 8; j++) {
    int idx = base + j;
    if (idx < NN) { off[idx] = run; run += v[j]; }
  }
}

__global__ void scan2_kernel(int* __restrict__ blksum, int* __restrict__ off) {
  if (threadIdx.x == 0) {
    int run = 0;
    for (int i = 0; i < NSCAN; i++) { int t = blksum[i]; blksum[i] = run; run += t; }
    off[NN] = NE;
  }
}

__global__ __launch_bounds__(256) void scan3_kernel(int* __restrict__ off,
                                                    const int* __restrict__ blksum) {
  const int base = blockIdx.x * SCAN_CHUNK + threadIdx.x * 8;
  const int add = blksum[blockIdx.x];
#pragma unroll
  for (int j = 0; j < 8; j++) {
    int idx = base + j;
    if (idx < NN) off[idx] += add;
  }
}

// scatter edges into dst-sorted order; srcs only (norm recomputed in gathers)
__global__ __launch_bounds__(256) void permute_kernel(const int* __restrict__ src,
                                                      const int* __restrict__ dst,
                                                      int* __restrict__ cur,
                                                      int* __restrict__ srcs) {
  int e = blockIdx.x * 256 + threadIdx.x;
  if (e >= NE) return;
  int p = atomicAdd(&cur[dst[e]], 1);
  srcs[p] = src[e];
}

// ---------------------------------------------------------------------------
// MFMA GEMM: H[rows x C] = X[rows x 128] @ W[128 x C], bf16 MFMA 16x16x32.
// 64 rows/block, 256 thr (4 waves); wave w owns rows w*16..w*16+15, all C cols.
// LDS stride 136 ushorts (pad). Fragment layouts verified r11 (absmax ok).
// ---------------------------------------------------------------------------

template <int C, bool BF16_IN>
__global__ __launch_bounds__(256) void gemm_mfma_kernel(const void* __restrict__ Xv,
                                                        const float* __restrict__ W,
                                                        unsigned short* __restrict__ H,
                                                        int nrows) {
  constexpr int STR = 136;
  __shared__ unsigned short Xs[64 * STR];
  __shared__ unsigned short Wt[C * STR];   // Wt[n][k] = W[k][n]
  const int row0 = blockIdx.x * 64;
  const int nr = min(64, nrows - row0);
  const int tid = threadIdx.x;

  // stage W^T as bf16: thread t handles (n, kk): k = 2*kk, 2*kk+1
  for (int t = tid; t < C * 64; t += 256) {
    int n = t % C, kk = t / C;
    unsigned pk = ((unsigned)f2bf(W[(2 * kk + 1) * C + n]) << 16) | f2bf(W[(2 * kk) * C + n]);
    *(unsigned*)&Wt[n * STR + 2 * kk] = pk;
  }
  // stage X as bf16: thread t handles (row, kp): k = 2*kp, 2*kp+1
  if (BF16_IN) {
    const unsigned* X = (const unsigned*)Xv + (size_t)row0 * 64;
    for (int t = tid; t < 64 * 64; t += 256) {
      int r = t >> 6, kp = t & 63;
      unsigned p = (r < nr) ? X[r * 64 + kp] : 0u;
      *(unsigned*)&Xs[r * STR + 2 * kp] = p;
    }
  } else {
    const float* X = (const float*)Xv + (size_t)row0 * 128;
    for (int t = tid; t < 64 * 64; t += 256) {
      int r = t >> 6, kp = t & 63;
      unsigned p = 0u;
      if (r < nr) {
        float2 v = *(const float2*)&X[r * 128 + 2 * kp];
        p = ((unsigned)f2bf(v.y) << 16) | f2bf(v.x);
      }
      *(unsigned*)&Xs[r * STR + 2 * kp] = p;
    }
  }
  __syncthreads();

  const int w  = tid >> 6;
  const int l  = tid & 63;
  const int lr = l & 15;
  const int lk = l >> 4;
  constexpr int NT = C / 16;

  f32x4 acc[NT];
#pragma unroll
  for (int nt = 0; nt < NT; nt++) acc[nt] = (f32x4){0.f, 0.f, 0.f, 0.f};

  short8v afr[4];
  const int arow = w * 16 + lr;
#pragma unroll
  for (int ks = 0; ks < 4; ks++)
    afr[ks] = *(const short8v*)&Xs[arow * STR + ks * 32 + lk * 8];

#pragma unroll
  for (int nt = 0; nt < NT; nt++) {
    const int ncol = nt * 16 + lr;
#pragma unroll
    for (int ks = 0; ks < 4; ks++) {
      short8v bfr = *(const short8v*)&Wt[ncol * STR + ks * 32 + lk * 8];
      acc[nt] = __builtin_amdgcn_mfma_f32_16x16x32_bf16(afr[ks], bfr, acc[nt], 0, 0, 0);
    }
  }

#pragma unroll
  for (int nt = 0; nt < NT; nt++) {
#pragma unroll
    for (int r = 0; r < 4; r++) {
      int row = w * 16 + lk * 4 + r;
      if (row < nr) H[(size_t)(row0 + row) * C + nt * 16 + lr] = f2bf(acc[nt][r]);
    }
  }
}

// ---------------------------------------------------------------------------
// Gather layer 1 (unroll x8): hd = dropout(relu(sum h[s]*dinv[s]*di + self + b1))
// 1 wave per node, 2 bf16 channels per lane. nrm computed inline from dinv.
// ---------------------------------------------------------------------------

__global__ __launch_bounds__(256) void gather1_kernel(const int* __restrict__ off,
                                                      const int* __restrict__ srcs,
                                                      const unsigned* __restrict__ hb,
                                                      const float* __restrict__ dinv,
                                                      const float* __restrict__ b1,
                                                      unsigned* __restrict__ hd) {
  int nid = blockIdx.x * 4 + (threadIdx.x >> 6);
  if (nid >= NN) return;
  int c = threadIdx.x & 63;
  float di = dinv[nid];
  unsigned hp = hb[(size_t)nid * 64 + c];
  float a0 = lo16(hp) * di * di;
  float a1 = hi16(hp) * di * di;
  int beg = off[nid], end = off[nid + 1];
  int e = beg;
  for (; e + 8 <= end; e += 8) {
    int s[8]; float w[8]; unsigned p[8];
#pragma unroll
    for (int j = 0; j < 8; j++) s[j] = srcs[e + j];
#pragma unroll
    for (int j = 0; j < 8; j++) w[j] = dinv[s[j]] * di;
#pragma unroll
    for (int j = 0; j < 8; j++) p[j] = hb[(size_t)s[j] * 64 + c];
#pragma unroll
    for (int j = 0; j < 8; j++) {
      a0 = fmaf(lo16(p[j]), w[j], a0);
      a1 = fmaf(hi16(p[j]), w[j], a1);
    }
  }
  for (; e < end; e++) {
    int s = srcs[e];
    float w = dinv[s] * di;
    unsigned p = hb[(size_t)s * 64 + c];
    a0 = fmaf(lo16(p), w, a0);
    a1 = fmaf(hi16(p), w, a1);
  }
  a0 += b1[2 * c];
  a1 += b1[2 * c + 1];
  a0 = fmaxf(a0, 0.f);
  a1 = fmaxf(a1, 0.f);
  unsigned i0 = (unsigned)nid * 128u + 2u * (unsigned)c;
  a0 = dropout_keep(i0)      ? 2.f * a0 : 0.f;
  a1 = dropout_keep(i0 + 1u) ? 2.f * a1 : 0.f;
  hd[(size_t)nid * 64 + c] = ((unsigned)f2bf(a1) << 16) | f2bf(a0);
}

// ---------------------------------------------------------------------------
// Gather layer 2 (unroll x8): out = sum h2[s]*dinv[s]*di + self + b2  (fp32)
// 1 wave per node, 1 channel per lane.
// ---------------------------------------------------------------------------

__global__ __launch_bounds__(256) void gather2_kernel(const int* __restrict__ off,
                                                      const int* __restrict__ srcs,
                                                      const unsigned short* __restrict__ h2b,
                                                      const float* __restrict__ dinv,
                                                      const float* __restrict__ b2,
                                                      float* __restrict__ out) {
  int nid = blockIdx.x * 4 + (threadIdx.x >> 6);
  if (nid >= NN) return;
  int c = threadIdx.x & 63;
  float di = dinv[nid];
  float acc = bf2f(h2b[(size_t)nid * 64 + c]) * di * di;
  int beg = off[nid], end = off[nid + 1];
  int e = beg;
  for (; e + 8 <= end; e += 8) {
    int s[8]; float w[8]; float v[8];
#pragma unroll
    for (int j = 0; j < 8; j++) s[j] = srcs[e + j];
#pragma unroll
    for (int j = 0; j < 8; j++) w[j] = dinv[s[j]] * di;
#pragma unroll
    for (int j = 0; j < 8; j++) v[j] = bf2f(h2b[(size_t)s[j] * 64 + c]);
#pragma unroll
    for (int j = 0; j < 8; j++) acc = fmaf(v[j], w[j], acc);
  }
  for (; e < end; e++) {
    int s = srcs[e];
    acc = fmaf(bf2f(h2b[(size_t)s * 64 + c]), dinv[s] * di, acc);
  }
  out[(size_t)nid * 64 + c] = acc + b2[c];
}

// ---------------------------------------------------------------------------

extern "C" void kernel_launch(void* const* d_in, const int* in_sizes, int n_in,
                              void* d_out, int out_size, void* d_ws, size_t ws_size,
                              hipStream_t stream) {
  const float* x  = (const float*)d_in[0];
  const int*   ei = (const int*)d_in[1];
  const float* W1 = (const float*)d_in[2];
  const float* b1 = (const float*)d_in[3];
  const float* W2 = (const float*)d_in[4];
  const float* b2 = (const float*)d_in[5];
  float* out = (float*)d_out;

  const int* src = ei;
  const int* dst = ei + NE;

  char* p = (char*)d_ws;
  auto take = [&](size_t bytes) { char* q = p; p += (bytes + 15) & ~size_t(15); return q; };
  int*      cnt    = (int*)take(sizeof(int) * NN);
  int*      cur    = (int*)take(sizeof(int) * NN);
  int*      off    = (int*)take(sizeof(int) * (NN + 1));
  int*      blksum = (int*)take(sizeof(int) * NSCAN);
  float*    dinv   = (float*)take(sizeof(float) * NN);
  int*      srcs   = (int*)take(sizeof(int) * NE);
  unsigned* hb     = (unsigned*)take(sizeof(unsigned) * (size_t)NN * 64);   // h  bf16x2
  unsigned* hd     = (unsigned*)take(sizeof(unsigned) * (size_t)NN * 64);   // hd bf16x2
  unsigned* h2b    = (unsigned*)take(sizeof(unsigned) * (size_t)NN * 32);   // h2 bf16x2

  // CSR build
  hipMemsetAsync(cnt, 0, sizeof(int) * NN, stream);
  hist_kernel<<<(NE + 255) / 256, 256, 0, stream>>>(dst, cnt);
  scan1_kernel<<<NSCAN, 256, 0, stream>>>(cnt, off, blksum, dinv);
  scan2_kernel<<<1, 64, 0, stream>>>(blksum, off);
  scan3_kernel<<<NSCAN, 256, 0, stream>>>(off, blksum);
  hipMemcpyAsync(cur, off, sizeof(int) * NN, hipMemcpyDeviceToDevice, stream);
  permute_kernel<<<(NE + 255) / 256, 256, 0, stream>>>(src, dst, cur, srcs);

  // layer 1
  gemm_mfma_kernel<128, false><<<(NN + 63) / 64, 256, 0, stream>>>(
      x, W1, (unsigned short*)hb, NN);
  gather1_kernel<<<(NN + 3) / 4, 256, 0, stream>>>(off, srcs, hb, dinv, b1, hd);

  // layer 2
  gemm_mfma_kernel<64, true><<<(NN + 63) / 64, 256, 0, stream>>>(
      hd, W2, (unsigned short*)h2b, NN);
  gather2_kernel<<<(NN + 3) / 4, 256, 0, stream>>>(
      off, srcs, (const unsigned short*)h2b, dinv, b2, out);
}